// Round 21
// baseline (373.236 us; speedup 1.0000x reference)
//
#include <hip/hip_runtime.h>
#include <math.h>

#define NEGC 1e10f
#define EPSF 1e-8f

// problem sizes
#define NB 128
#define NL 48
#define NA 16
#define ND 256
#define NH 128
#define NS 47
#define PB_STRIDE (NL*ND)

// ws float offsets
#define WS_WT   0                 // wT[d][e] = w_sem[e][d] (256x256)
#define WS_INVN 65536             // [B][48] initial inverse norms
#define WS_LOG  (65536+6144)      // [B][48] initial logits
#define WS_PHYS (65536+12288)     // [B][48][256] sem0 rows

// out float offsets (features, lefts, rights, out_word, tree_idx, tree_probs, span_bounds)
#define O_FEAT  0
#define O_LEFT  1540096
#define O_RIGHT 3080192
#define O_WORD  4620288
#define O_TIDX  6193152
#define O_TP    6199168
#define O_SPAN  6205184

// LDS-only barrier (no vmcnt drain; all in-loop cross-thread deps are LDS)
__device__ __forceinline__ void ldsbar() {
  asm volatile("s_waitcnt lgkmcnt(0)" ::: "memory");
  __builtin_amdgcn_s_barrier();
  __builtin_amdgcn_sched_barrier(0);
}

// volatile asm global load: cannot be rematerialized or sunk by the compiler
#define GLOAD4(dst, addr) asm volatile("global_load_dwordx4 %0, %1, off" : "=v"(dst) : "v"(addr))

// ---------------- K0: w_sem transpose ----------------
__global__ __launch_bounds__(256) void k_transpose(const float* __restrict__ w_sem,
                                                   float* __restrict__ ws) {
  int blk = blockIdx.x, t = threadIdx.x;
  ws[WS_WT + blk*256 + t] = w_sem[t*256 + blk];
}

// ---------------- K1: sem0 = maskedmax_a(x @ w_sem^T), + row inverse norms ----------------
// r17 structure (dead-tile skip) + FORCED w double-buffer: GLOAD4 asm prefetches the next
// d-step's 4 w-rows before the FMA block; s_waitcnt vmcnt(0)+sched_barrier after it.
// r9's version of this was silently rematerialized by the compiler (VGPR stayed 64);
// the asm makes it real. acc 64 + w cur/next 32 VGPR ~= 112 < 128 cap at (128,4).
__global__ __launch_bounds__(128, 4) void k_sem0(const float* __restrict__ x,
                                                 const int* __restrict__ lengths,
                                                 const float* __restrict__ amask,
                                                 float* __restrict__ ws,
                                                 float* __restrict__ out) {
  __shared__ float xs[2*NA*128];   // 16 KB
  __shared__ float pen[2*NA];
  int bl0 = blockIdx.x * 2;
  int t = threadIdx.x;
  int wv = t >> 6;
  int c = t & 63;
  int bl = bl0 + wv;
  int b = bl / NL, l = bl - b*NL;
  int l0 = bl0 % NL;
  int lenB = lengths[bl0 / NL];
  int e0 = c*4;

  if (l0 >= lenB) {
    float4 z = make_float4(0.f, 0.f, 0.f, 0.f);
    *(float4*)(ws + WS_PHYS + (size_t)b*PB_STRIDE + l*ND + e0) = z;
    *(float4*)(out + O_WORD + (size_t)bl*ND + e0) = z;
    if (c == 0) ws[WS_INVN + bl] = 1.0f / (sqrtf(0.f) + EPSF);
    return;
  }
  bool live  = (l < lenB);
  bool live1 = (l0 + 1 < lenB);

  if (t < 2*NA) pen[t] = -NEGC * (1.0f - amask[(size_t)(bl0 + (t >> 4))*NA + (t & 15)]);
  float4* xs4 = (float4*)xs;
  const float* wt = ws + WS_WT;
  float acc[NA][4];
#pragma unroll
  for (int a = 0; a < NA; ++a) { acc[a][0]=0.f; acc[a][1]=0.f; acc[a][2]=0.f; acc[a][3]=0.f; }
  bool va[NA];

  // w double-buffer prologue (global d row 0)
  float4 cw0, cw1, cw2, cw3, nw0, nw1, nw2, nw3;
  {
    const float* wr = wt + e0;
    cw0 = *(const float4*)(wr);
    cw1 = *(const float4*)(wr + ND);
    cw2 = *(const float4*)(wr + 2*ND);
    cw3 = *(const float4*)(wr + 3*ND);
  }

  for (int p = 0; p < 2; ++p) {
    if (p) __syncthreads();
#pragma unroll
    for (int r = 0; r < 8; ++r) {
      int f = t + 128*r;
      int tile = f >> 9, rem = f & 511;
      int a = rem >> 5, dq = rem & 31;
      if (tile == 0 || live1) {
        const float4* xg4 = (const float4*)(x + (size_t)(bl0 + tile)*(NA*ND));
        xs4[f] = xg4[a*64 + p*32 + dq];
      }
    }
    __syncthreads();
    if (p == 0) {
#pragma unroll
      for (int a = 0; a < NA; ++a) va[a] = live && (pen[wv*NA + a] == 0.0f);
    }
    if (live) {
      for (int d0 = 0; d0 < 128; d0 += 4) {
        int g = p*128 + d0;
        bool pf = (g < 252);
        if (pf) {
          const float* wr = wt + (size_t)(g + 4)*ND + e0;
          GLOAD4(nw0, wr);
          GLOAD4(nw1, wr + ND);
          GLOAD4(nw2, wr + 2*ND);
          GLOAD4(nw3, wr + 3*ND);
        }
#pragma unroll
        for (int a = 0; a < NA; ++a) {
          if (va[a]) {
            float4 xa = xs4[wv*512 + a*32 + (d0 >> 2)];
            acc[a][0] = fmaf(xa.x, cw0.x, acc[a][0]);
            acc[a][1] = fmaf(xa.x, cw0.y, acc[a][1]);
            acc[a][2] = fmaf(xa.x, cw0.z, acc[a][2]);
            acc[a][3] = fmaf(xa.x, cw0.w, acc[a][3]);
            acc[a][0] = fmaf(xa.y, cw1.x, acc[a][0]);
            acc[a][1] = fmaf(xa.y, cw1.y, acc[a][1]);
            acc[a][2] = fmaf(xa.y, cw1.z, acc[a][2]);
            acc[a][3] = fmaf(xa.y, cw1.w, acc[a][3]);
            acc[a][0] = fmaf(xa.z, cw2.x, acc[a][0]);
            acc[a][1] = fmaf(xa.z, cw2.y, acc[a][1]);
            acc[a][2] = fmaf(xa.z, cw2.z, acc[a][2]);
            acc[a][3] = fmaf(xa.z, cw2.w, acc[a][3]);
            acc[a][0] = fmaf(xa.w, cw3.x, acc[a][0]);
            acc[a][1] = fmaf(xa.w, cw3.y, acc[a][1]);
            acc[a][2] = fmaf(xa.w, cw3.z, acc[a][2]);
            acc[a][3] = fmaf(xa.w, cw3.w, acc[a][3]);
          }
        }
        if (pf) {
          asm volatile("s_waitcnt vmcnt(0)" ::: "memory");
          __builtin_amdgcn_sched_barrier(0);
          cw0 = nw0; cw1 = nw1; cw2 = nw2; cw3 = nw3;
        }
      }
    }
  }
  float m0 = -INFINITY, m1 = -INFINITY, m2 = -INFINITY, m3 = -INFINITY;
#pragma unroll
  for (int a = 0; a < NA; ++a) {
    if (va[a]) {
      m0 = fmaxf(m0, acc[a][0]);
      m1 = fmaxf(m1, acc[a][1]);
      m2 = fmaxf(m2, acc[a][2]);
      m3 = fmaxf(m3, acc[a][3]);
    }
  }
  if (!live) { m0 = 0.f; m1 = 0.f; m2 = 0.f; m3 = 0.f; }
  float* prow = ws + WS_PHYS + (size_t)b*PB_STRIDE + l*ND;
  *(float4*)(prow + e0) = make_float4(m0, m1, m2, m3);
  float wm = live ? 1.0f : 0.0f;
  *(float4*)(out + O_WORD + (size_t)bl*ND + e0) = make_float4(m0*wm, m1*wm, m2*wm, m3*wm);
  float s2 = m0*m0 + m1*m1 + m2*m2 + m3*m3;
#pragma unroll
  for (int off = 32; off; off >>= 1) s2 += __shfl_down(s2, off);
  if (c == 0) ws[WS_INVN + bl] = 1.0f / (sqrtf(s2) + EPSF);
}

// ---------------- K2: initial logits, clamped to live positions p < len-1 ----------------
__global__ __launch_bounds__(512, 1) void k_prelogits(float* __restrict__ ws,
                                                      const int* __restrict__ lengths,
                                                      const float* __restrict__ w1g,
                                                      const float* __restrict__ b1g,
                                                      const float* __restrict__ w2g) {
  __shared__ float rows[25*ND];
  __shared__ float part[4*8*NH];
  __shared__ float invl[25];
  __shared__ float b1s[NH];
  __shared__ float w2s[NH];
  int bid = blockIdx.x;
  int b = bid >> 1, h = bid & 1;
  int p0 = h*24;
  int np = h ? 23 : 24;
  int nrows = h ? 24 : 25;
  int t = threadIdx.x;
  int lane = t & 63, wv = t >> 6;
  int j = t & 127, q = t >> 7;

  int lenB = lengths[b];
  int npl = lenB - 1 - p0;
  if (npl > np) npl = np;
  if (npl <= 0) return;

  float w1f[128];
  {
    const float4* wsrc = (const float4*)(w1g + (size_t)j*512 + q*128);
#pragma unroll
    for (int kk = 0; kk < 32; ++kk) {
      float4 v = wsrc[kk];
      w1f[4*kk+0] = v.x; w1f[4*kk+1] = v.y; w1f[4*kk+2] = v.z; w1f[4*kk+3] = v.w;
    }
  }
#pragma unroll
  for (int kk = 0; kk < 32; ++kk)
    asm volatile("" : "+v"(w1f[4*kk+0]), "+v"(w1f[4*kk+1]), "+v"(w1f[4*kk+2]), "+v"(w1f[4*kk+3]));

  if (t < NH) { b1s[t] = b1g[t]; w2s[t] = w2g[t]; }
  if (t < nrows) invl[t] = ws[WS_INVN + b*48 + p0 + t];
  {
    const float4* pg4 = (const float4*)(ws + WS_PHYS + (size_t)b*PB_STRIDE);
    float4* rows4 = (float4*)rows;
    int n4 = nrows * 64;
    for (int u = t; u < n4; u += 512) rows4[u] = pg4[p0*64 + u];
  }
  __syncthreads();

  for (int ct = 0; ct < 3; ++ct) {
    if (ct*8 >= npl) break;
#pragma unroll
    for (int c = 0; c < 8; ++c) {
      int pp = ct*8 + c;
      if (pp < npl) {
        int rloc = (q < 2) ? pp + 1 : pp;
        const float4* rp4 = (const float4*)(rows + rloc*ND + (q & 1)*128);
        float ax = 0.f, ay = 0.f, az = 0.f, aw = 0.f;
#pragma unroll
        for (int kk = 0; kk < 32; ++kk) {
          float4 rv = rp4[kk];
          ax = fmaf(w1f[4*kk+0], rv.x, ax);
          ay = fmaf(w1f[4*kk+1], rv.y, ay);
          az = fmaf(w1f[4*kk+2], rv.z, az);
          aw = fmaf(w1f[4*kk+3], rv.w, aw);
        }
        part[(q*8 + c)*NH + j] = (ax + ay) + (az + aw);
      }
    }
    __syncthreads();
    int pp = ct*8 + wv;
    if (pp < npl) {
      float inR = invl[pp + 1], inL = invl[pp];
      float pr0 = part[(0*8+wv)*NH + lane]      + part[(1*8+wv)*NH + lane];
      float pl0 = part[(2*8+wv)*NH + lane]      + part[(3*8+wv)*NH + lane];
      float pr1 = part[(0*8+wv)*NH + lane + 64] + part[(1*8+wv)*NH + lane + 64];
      float pl1 = part[(2*8+wv)*NH + lane + 64] + part[(3*8+wv)*NH + lane + 64];
      float h0 = fmaf(inR, pr0, fmaf(inL, pl0, b1s[lane]));
      float h1 = fmaf(inR, pr1, fmaf(inL, pl1, b1s[lane + 64]));
      h0 = fmaxf(h0, 0.f); h1 = fmaxf(h1, 0.f);
      float v = w2s[lane]*h0 + w2s[lane + 64]*h1;
#pragma unroll
      for (int off = 32; off; off >>= 1) v += __shfl_down(v, off);
      if (lane == 0) ws[WS_LOG + b*48 + p0 + pp] = v;
    }
    __syncthreads();
  }
}

// ---------------- K3: greedy merge scan — 1024 threads, k-split 8 ways; finalize+argmax
// merged into wave 0 (one barrier fewer per live iteration: B1,B3,B4,B5) ----------------
__global__ __launch_bounds__(1024, 1) void k_tree(const int* __restrict__ lengths,
                                                  float* __restrict__ ws,
                                                  const float* __restrict__ w1g,
                                                  const float* __restrict__ b1g,
                                                  const float* __restrict__ w2g,
                                                  float* __restrict__ out) {
  __shared__ float rows[NL*ND];      // 48 KB
  __shared__ float part[16*NH];      // 8 KB
  __shared__ float logits[48];
  __shared__ int physIdx[48];
  __shared__ int lbA[48];
  __shared__ int rbA[48];
  __shared__ float invn[48];
  __shared__ float b1s[NH];
  __shared__ float w2s[NH];
  __shared__ float red[8];
  __shared__ int s_idx, s_rL;
  __shared__ float s_tp, s_max;

  int b = blockIdx.x;
  int t = threadIdx.x;               // 0..1023
  int lane = t & 63, wv = t >> 6;    // 16 waves
  int j = t & 127, s8 = t >> 7;      // output unit j, k-segment s8 in [0,8)
  int len = lengths[b];

  // w1 segment pinned in registers: 64 VGPR
  float w1f[64];
  {
    const float4* wsrc = (const float4*)(w1g + (size_t)j*512 + s8*64);
#pragma unroll
    for (int kk = 0; kk < 16; ++kk) {
      float4 v = wsrc[kk];
      w1f[4*kk+0] = v.x; w1f[4*kk+1] = v.y; w1f[4*kk+2] = v.z; w1f[4*kk+3] = v.w;
    }
  }
#pragma unroll
  for (int kk = 0; kk < 16; ++kk)
    asm volatile("" : "+v"(w1f[4*kk+0]), "+v"(w1f[4*kk+1]), "+v"(w1f[4*kk+2]), "+v"(w1f[4*kk+3]));

  if (t < NH) { b1s[t] = b1g[t]; w2s[t] = w2g[t]; }
  if (t < 48) { physIdx[t] = t; lbA[t] = t; rbA[t] = t; invn[t] = ws[WS_INVN + b*48 + t]; }
  if (t < 47) logits[t] = ws[WS_LOG + b*48 + t];
  {
    const float4* pg4 = (const float4*)(ws + WS_PHYS + (size_t)b*PB_STRIDE);
    float4* rows4 = (float4*)rows;
    for (int u = t; u < NL*64; u += 1024) rows4[u] = pg4[u];
  }
  __syncthreads();

  auto gemv_pos = [&](int pos, int slot) {
    int r = (s8 < 4) ? physIdx[pos + 1] : physIdx[pos];
    const float4* rp4 = (const float4*)(rows + r*ND + (s8 & 3)*64);
    float ax = 0.f, ay = 0.f, az = 0.f, aw = 0.f;
#pragma unroll
    for (int kk = 0; kk < 16; ++kk) {
      float4 rv = rp4[kk];
      ax = fmaf(w1f[4*kk+0], rv.x, ax);
      ay = fmaf(w1f[4*kk+1], rv.y, ay);
      az = fmaf(w1f[4*kk+2], rv.z, az);
      aw = fmaf(w1f[4*kk+3], rv.w, aw);
    }
    part[(s8*2 + slot)*NH + j] = (ax + ay) + (az + aw);
  };

  int pidx = -1;
  for (int i = 0; i < NS; ++i) {
    int valid = len - 1 - i; if (valid < 0) valid = 0;
    // ---- R1: deferred invn update for previous merged slot ----
    if (i > 0 && t == 0)
      invn[s_rL] = 1.0f / (sqrtf(red[4]+red[5]+red[6]+red[7]) + EPSF);
    if (valid >= 2) {
      if (i > 0) {
        int pos0 = -1, pos1 = -1, np = 0;
        if (pidx > 0) { pos0 = pidx - 1; np = 1; }
        if (pidx <= valid - 1) { if (np) pos1 = pidx; else pos0 = pidx; ++np; }
        gemv_pos(pos0, 0);
        if (np > 1) gemv_pos(pos1, 1);
        ldsbar();                              // B1 (LDS: part, invn)
        // ---- wave 0: dual finalize + argmax with in-register overrides ----
        if (wv == 0) {
          float inR0 = invn[physIdx[pos0 + 1]], inL0 = invn[physIdx[pos0]];
          float pr0 = (part[(0*2+0)*NH + lane]      + part[(1*2+0)*NH + lane])
                    + (part[(2*2+0)*NH + lane]      + part[(3*2+0)*NH + lane]);
          float pl0 = (part[(4*2+0)*NH + lane]      + part[(5*2+0)*NH + lane])
                    + (part[(6*2+0)*NH + lane]      + part[(7*2+0)*NH + lane]);
          float pr1 = (part[(0*2+0)*NH + lane + 64] + part[(1*2+0)*NH + lane + 64])
                    + (part[(2*2+0)*NH + lane + 64] + part[(3*2+0)*NH + lane + 64]);
          float pl1 = (part[(4*2+0)*NH + lane + 64] + part[(5*2+0)*NH + lane + 64])
                    + (part[(6*2+0)*NH + lane + 64] + part[(7*2+0)*NH + lane + 64]);
          float h0 = fmaf(inR0, pr0, fmaf(inL0, pl0, b1s[lane]));
          float h1 = fmaf(inR0, pr1, fmaf(inL0, pl1, b1s[lane + 64]));
          h0 = fmaxf(h0, 0.f); h1 = fmaxf(h1, 0.f);
          float v0 = w2s[lane]*h0 + w2s[lane + 64]*h1;
          float v1 = 0.f;
          if (np > 1) {
            float inR1 = invn[physIdx[pos1 + 1]], inL1 = invn[physIdx[pos1]];
            float qr0 = (part[(0*2+1)*NH + lane]      + part[(1*2+1)*NH + lane])
                      + (part[(2*2+1)*NH + lane]      + part[(3*2+1)*NH + lane]);
            float ql0 = (part[(4*2+1)*NH + lane]      + part[(5*2+1)*NH + lane])
                      + (part[(6*2+1)*NH + lane]      + part[(7*2+1)*NH + lane]);
            float qr1 = (part[(0*2+1)*NH + lane + 64] + part[(1*2+1)*NH + lane + 64])
                      + (part[(2*2+1)*NH + lane + 64] + part[(3*2+1)*NH + lane + 64]);
            float ql1 = (part[(4*2+1)*NH + lane + 64] + part[(5*2+1)*NH + lane + 64])
                      + (part[(6*2+1)*NH + lane + 64] + part[(7*2+1)*NH + lane + 64]);
            float g0 = fmaf(inR1, qr0, fmaf(inL1, ql0, b1s[lane]));
            float g1 = fmaf(inR1, qr1, fmaf(inL1, ql1, b1s[lane + 64]));
            g0 = fmaxf(g0, 0.f); g1 = fmaxf(g1, 0.f);
            v1 = w2s[lane]*g0 + w2s[lane + 64]*g1;
          }
#pragma unroll
          for (int off = 32; off; off >>= 1) { v0 += __shfl_down(v0, off); v1 += __shfl_down(v1, off); }
          float fresh0 = __shfl(v0, 0);
          float fresh1 = __shfl(v1, 0);
          // argmax over domain with overrides (stale LDS reads are overridden in-register)
          float ev = (lane < valid) ? logits[lane] : -INFINITY;
          if (lane == pos0) ev = fresh0;
          if (np > 1 && lane == pos1) ev = fresh1;
          float v = ev; int bi = lane;
#pragma unroll
          for (int off = 32; off; off >>= 1) {
            float ov = __shfl_down(v, off);
            int  oi = __shfl_down(bi, off);
            if (ov > v || (ov == v && oi < bi)) { v = ov; bi = oi; }
          }
          if (lane == 0) {
            s_idx = bi; s_max = v;
            logits[pos0] = fresh0;
            if (np > 1) logits[pos1] = fresh1;
          }
        }
      } else {
        // i == 0: argmax straight from prelogits
        if (wv == 0) {
          float v = (lane < valid) ? logits[lane] : -INFINITY;
          int bi = lane;
#pragma unroll
          for (int off = 32; off; off >>= 1) {
            float ov = __shfl_down(v, off);
            int  oi = __shfl_down(bi, off);
            if (ov > v || (ov == v && oi < bi)) { v = ov; bi = oi; }
          }
          if (lane == 0) { s_idx = bi; s_max = v; }
        }
      }
    } else {
      // valid==1: idx=0, tp=1. valid==0: all logits bitwise -1e10 -> uniform: idx=0, tp=1/47.
      if (t == 0) { s_idx = 0; s_tp = (valid == 1) ? 1.0f : (1.0f/47.0f); }
    }
    ldsbar();                                  // B3 (LDS: s_idx, s_max, logits)
    int idx = s_idx;
    // ---- R4: merge gather (waves 0-3) || softmax sum (wave 4) || pre-reads (wave 5) ----
    int rL = 0, rR = 0; float slv = 0.f, srv = 0.f, inL = 0.f, inR = 0.f, sumv = 0.f;
    if (t < ND) {
      rL = physIdx[idx]; rR = physIdx[idx + 1];
      slv = rows[rL*ND + t]; srv = rows[rR*ND + t];
      inL = invn[rL]; inR = invn[rR];
      sumv = slv + srv;
      float q2 = sumv * sumv;
#pragma unroll
      for (int off = 32; off; off >>= 1) q2 += __shfl_down(q2, off);
      if (lane == 0) red[wv] = q2;
    }
    int sp0 = 0, sp1 = 0;
    if (t == 0) { s_rL = rL; sp0 = lbA[idx]; sp1 = rbA[idx + 1]; }
    if (wv == 4 && valid >= 2) {
      float ee = (lane < valid) ? expf(logits[lane] - s_max) : 0.f;
#pragma unroll
      for (int off = 32; off; off >>= 1) ee += __shfl_down(ee, off);
      if (lane == 0) s_tp = 1.0f / ee;
    }
    int tt = t - 320;
    int pv = 0, lv = 0, rv_ = 0; float gv = 0.f;
    if (wv == 5 && tt < 47) { pv = physIdx[tt+1]; lv = lbA[tt+1]; rv_ = rbA[tt+1]; gv = logits[tt+1]; }
    ldsbar();                                  // B4 (LDS: red, s_tp, pre-reads)
    // ---- R5: outputs, row update, bookkeeping shifts ----
    float undone = valid > 0 ? 1.0f : 0.0f;
    if (t < ND) {
      float invns = 1.0f / (sqrtf(red[0]+red[1]+red[2]+red[3]) + EPSF);
      float featv = sumv * invns;
      int ob = (i*NB + b)*ND + t;
      out[O_FEAT  + ob] = featv * undone;
      out[O_LEFT  + ob] = slv * inL * undone;
      out[O_RIGHT + ob] = srv * inR * undone;
      rows[rL*ND + t] = featv;
      float q3 = featv * featv;
#pragma unroll
      for (int off = 32; off; off >>= 1) q3 += __shfl_down(q3, off);
      if (lane == 0) red[4 + wv] = q3;
    }
    if (t == 0) {
      out[O_TIDX + i*NB + b] = (float)idx;
      out[O_TP   + i*NB + b] = s_tp;
      out[O_SPAN + (i*NB + b)*2 + 0] = (float)sp0;
      out[O_SPAN + (i*NB + b)*2 + 1] = (float)sp1;
    }
    if (wv == 5 && tt < 47) {
      if (tt > idx) { physIdx[tt] = pv; lbA[tt] = lv; logits[tt] = gv; }
      if (tt >= idx) rbA[tt] = rv_;
    }
    ldsbar();                                  // B5 (LDS: rows/logits/bookkeeping/red)
    pidx = idx;
  }
}

extern "C" void kernel_launch(void* const* d_in, const int* in_sizes, int n_in,
                              void* d_out, int out_size, void* d_ws, size_t ws_size,
                              hipStream_t stream) {
  const float* x      = (const float*)d_in[0];
  const int*   lengths= (const int*)  d_in[1];
  const float* amask  = (const float*)d_in[2];
  const float* w_sem  = (const float*)d_in[3];
  const float* w1     = (const float*)d_in[4];
  const float* b1     = (const float*)d_in[5];
  const float* w2     = (const float*)d_in[6];
  float* out = (float*)d_out;
  float* ws  = (float*)d_ws;

  k_transpose<<<dim3(256), dim3(256), 0, stream>>>(w_sem, ws);
  k_sem0<<<dim3(NB*NL/2), dim3(128), 0, stream>>>(x, lengths, amask, ws, out);
  k_prelogits<<<dim3(256), dim3(512), 0, stream>>>(ws, lengths, w1, b1, w2);
  k_tree<<<dim3(NB), dim3(1024), 0, stream>>>(lengths, ws, w1, b1, w2, out);
}

// Round 22
// 326.841 us; speedup vs baseline: 1.1419x; 1.1419x over previous
//
#include <hip/hip_runtime.h>
#include <math.h>

#define NEGC 1e10f
#define EPSF 1e-8f

// problem sizes
#define NB 128
#define NL 48
#define NA 16
#define ND 256
#define NH 128
#define NS 47
#define PB_STRIDE (NL*ND)

// ws float offsets
#define WS_WT   0                 // wT[d][e] = w_sem[e][d] (256x256)
#define WS_INVN 65536             // [B][48] initial inverse norms
#define WS_LOG  (65536+6144)      // [B][48] initial logits
#define WS_PHYS (65536+12288)     // [B][48][256] sem0 rows

// out float offsets (features, lefts, rights, out_word, tree_idx, tree_probs, span_bounds)
#define O_FEAT  0
#define O_LEFT  1540096
#define O_RIGHT 3080192
#define O_WORD  4620288
#define O_TIDX  6193152
#define O_TP    6199168
#define O_SPAN  6205184

// LDS-only barrier (no vmcnt drain; all in-loop cross-thread deps are LDS)
__device__ __forceinline__ void ldsbar() {
  asm volatile("s_waitcnt lgkmcnt(0)" ::: "memory");
  __builtin_amdgcn_s_barrier();
  __builtin_amdgcn_sched_barrier(0);
}

// ---------------- K0: w_sem transpose ----------------
__global__ __launch_bounds__(256) void k_transpose(const float* __restrict__ w_sem,
                                                   float* __restrict__ ws) {
  int blk = blockIdx.x, t = threadIdx.x;
  ws[WS_WT + blk*256 + t] = w_sem[t*256 + blk];
}

// ---------------- K1: sem0 = maskedmax_a(x @ w_sem^T), + row inverse norms ----------------
// r17 version: r11 structure + dead-tile skip.
__global__ __launch_bounds__(128) void k_sem0(const float* __restrict__ x,
                                              const int* __restrict__ lengths,
                                              const float* __restrict__ amask,
                                              float* __restrict__ ws,
                                              float* __restrict__ out) {
  __shared__ float xs[2*NA*128];   // 16 KB
  __shared__ float pen[2*NA];
  int bl0 = blockIdx.x * 2;
  int t = threadIdx.x;
  int wv = t >> 6;
  int c = t & 63;
  int bl = bl0 + wv;
  int b = bl / NL, l = bl - b*NL;
  int l0 = bl0 % NL;
  int lenB = lengths[bl0 / NL];
  int e0 = c*4;

  if (l0 >= lenB) {
    float4 z = make_float4(0.f, 0.f, 0.f, 0.f);
    *(float4*)(ws + WS_PHYS + (size_t)b*PB_STRIDE + l*ND + e0) = z;
    *(float4*)(out + O_WORD + (size_t)bl*ND + e0) = z;
    if (c == 0) ws[WS_INVN + bl] = 1.0f / (sqrtf(0.f) + EPSF);
    return;
  }
  bool live  = (l < lenB);
  bool live1 = (l0 + 1 < lenB);

  if (t < 2*NA) pen[t] = -NEGC * (1.0f - amask[(size_t)(bl0 + (t >> 4))*NA + (t & 15)]);
  float4* xs4 = (float4*)xs;
  const float* wt = ws + WS_WT;
  float acc[NA][4];
#pragma unroll
  for (int a = 0; a < NA; ++a) { acc[a][0]=0.f; acc[a][1]=0.f; acc[a][2]=0.f; acc[a][3]=0.f; }
  bool va[NA];

  for (int p = 0; p < 2; ++p) {
    if (p) __syncthreads();
#pragma unroll
    for (int r = 0; r < 8; ++r) {
      int f = t + 128*r;
      int tile = f >> 9, rem = f & 511;
      int a = rem >> 5, dq = rem & 31;
      if (tile == 0 || live1) {
        const float4* xg4 = (const float4*)(x + (size_t)(bl0 + tile)*(NA*ND));
        xs4[f] = xg4[a*64 + p*32 + dq];
      }
    }
    __syncthreads();
    if (p == 0) {
#pragma unroll
      for (int a = 0; a < NA; ++a) va[a] = live && (pen[wv*NA + a] == 0.0f);
    }
    if (live) {
      for (int d0 = 0; d0 < 128; d0 += 4) {
        const float* wrow = wt + (size_t)(p*128 + d0)*ND + e0;
        float4 wr0 = *(const float4*)(wrow);
        float4 wr1 = *(const float4*)(wrow + ND);
        float4 wr2 = *(const float4*)(wrow + 2*ND);
        float4 wr3 = *(const float4*)(wrow + 3*ND);
#pragma unroll
        for (int a = 0; a < NA; ++a) {
          if (va[a]) {
            float4 xa = xs4[wv*512 + a*32 + (d0 >> 2)];
            acc[a][0] = fmaf(xa.x, wr0.x, acc[a][0]);
            acc[a][1] = fmaf(xa.x, wr0.y, acc[a][1]);
            acc[a][2] = fmaf(xa.x, wr0.z, acc[a][2]);
            acc[a][3] = fmaf(xa.x, wr0.w, acc[a][3]);
            acc[a][0] = fmaf(xa.y, wr1.x, acc[a][0]);
            acc[a][1] = fmaf(xa.y, wr1.y, acc[a][1]);
            acc[a][2] = fmaf(xa.y, wr1.z, acc[a][2]);
            acc[a][3] = fmaf(xa.y, wr1.w, acc[a][3]);
            acc[a][0] = fmaf(xa.z, wr2.x, acc[a][0]);
            acc[a][1] = fmaf(xa.z, wr2.y, acc[a][1]);
            acc[a][2] = fmaf(xa.z, wr2.z, acc[a][2]);
            acc[a][3] = fmaf(xa.z, wr2.w, acc[a][3]);
            acc[a][0] = fmaf(xa.w, wr3.x, acc[a][0]);
            acc[a][1] = fmaf(xa.w, wr3.y, acc[a][1]);
            acc[a][2] = fmaf(xa.w, wr3.z, acc[a][2]);
            acc[a][3] = fmaf(xa.w, wr3.w, acc[a][3]);
          }
        }
      }
    }
  }
  float m0 = -INFINITY, m1 = -INFINITY, m2 = -INFINITY, m3 = -INFINITY;
#pragma unroll
  for (int a = 0; a < NA; ++a) {
    if (va[a]) {
      m0 = fmaxf(m0, acc[a][0]);
      m1 = fmaxf(m1, acc[a][1]);
      m2 = fmaxf(m2, acc[a][2]);
      m3 = fmaxf(m3, acc[a][3]);
    }
  }
  if (!live) { m0 = 0.f; m1 = 0.f; m2 = 0.f; m3 = 0.f; }
  float* prow = ws + WS_PHYS + (size_t)b*PB_STRIDE + l*ND;
  *(float4*)(prow + e0) = make_float4(m0, m1, m2, m3);
  float wm = live ? 1.0f : 0.0f;
  *(float4*)(out + O_WORD + (size_t)bl*ND + e0) = make_float4(m0*wm, m1*wm, m2*wm, m3*wm);
  float s2 = m0*m0 + m1*m1 + m2*m2 + m3*m3;
#pragma unroll
  for (int off = 32; off; off >>= 1) s2 += __shfl_down(s2, off);
  if (c == 0) ws[WS_INVN + bl] = 1.0f / (sqrtf(s2) + EPSF);
}

// ---------------- K2: initial logits, clamped to live positions p < len-1 ----------------
__global__ __launch_bounds__(512, 1) void k_prelogits(float* __restrict__ ws,
                                                      const int* __restrict__ lengths,
                                                      const float* __restrict__ w1g,
                                                      const float* __restrict__ b1g,
                                                      const float* __restrict__ w2g) {
  __shared__ float rows[25*ND];
  __shared__ float part[4*8*NH];
  __shared__ float invl[25];
  __shared__ float b1s[NH];
  __shared__ float w2s[NH];
  int bid = blockIdx.x;
  int b = bid >> 1, h = bid & 1;
  int p0 = h*24;
  int np = h ? 23 : 24;
  int nrows = h ? 24 : 25;
  int t = threadIdx.x;
  int lane = t & 63, wv = t >> 6;
  int j = t & 127, q = t >> 7;

  int lenB = lengths[b];
  int npl = lenB - 1 - p0;
  if (npl > np) npl = np;
  if (npl <= 0) return;

  float w1f[128];
  {
    const float4* wsrc = (const float4*)(w1g + (size_t)j*512 + q*128);
#pragma unroll
    for (int kk = 0; kk < 32; ++kk) {
      float4 v = wsrc[kk];
      w1f[4*kk+0] = v.x; w1f[4*kk+1] = v.y; w1f[4*kk+2] = v.z; w1f[4*kk+3] = v.w;
    }
  }
#pragma unroll
  for (int kk = 0; kk < 32; ++kk)
    asm volatile("" : "+v"(w1f[4*kk+0]), "+v"(w1f[4*kk+1]), "+v"(w1f[4*kk+2]), "+v"(w1f[4*kk+3]));

  if (t < NH) { b1s[t] = b1g[t]; w2s[t] = w2g[t]; }
  if (t < nrows) invl[t] = ws[WS_INVN + b*48 + p0 + t];
  {
    const float4* pg4 = (const float4*)(ws + WS_PHYS + (size_t)b*PB_STRIDE);
    float4* rows4 = (float4*)rows;
    int n4 = nrows * 64;
    for (int u = t; u < n4; u += 512) rows4[u] = pg4[p0*64 + u];
  }
  __syncthreads();

  for (int ct = 0; ct < 3; ++ct) {
    if (ct*8 >= npl) break;
#pragma unroll
    for (int c = 0; c < 8; ++c) {
      int pp = ct*8 + c;
      if (pp < npl) {
        int rloc = (q < 2) ? pp + 1 : pp;
        const float4* rp4 = (const float4*)(rows + rloc*ND + (q & 1)*128);
        float ax = 0.f, ay = 0.f, az = 0.f, aw = 0.f;
#pragma unroll
        for (int kk = 0; kk < 32; ++kk) {
          float4 rv = rp4[kk];
          ax = fmaf(w1f[4*kk+0], rv.x, ax);
          ay = fmaf(w1f[4*kk+1], rv.y, ay);
          az = fmaf(w1f[4*kk+2], rv.z, az);
          aw = fmaf(w1f[4*kk+3], rv.w, aw);
        }
        part[(q*8 + c)*NH + j] = (ax + ay) + (az + aw);
      }
    }
    __syncthreads();
    int pp = ct*8 + wv;
    if (pp < npl) {
      float inR = invl[pp + 1], inL = invl[pp];
      float pr0 = part[(0*8+wv)*NH + lane]      + part[(1*8+wv)*NH + lane];
      float pl0 = part[(2*8+wv)*NH + lane]      + part[(3*8+wv)*NH + lane];
      float pr1 = part[(0*8+wv)*NH + lane + 64] + part[(1*8+wv)*NH + lane + 64];
      float pl1 = part[(2*8+wv)*NH + lane + 64] + part[(3*8+wv)*NH + lane + 64];
      float h0 = fmaf(inR, pr0, fmaf(inL, pl0, b1s[lane]));
      float h1 = fmaf(inR, pr1, fmaf(inL, pl1, b1s[lane + 64]));
      h0 = fmaxf(h0, 0.f); h1 = fmaxf(h1, 0.f);
      float v = w2s[lane]*h0 + w2s[lane + 64]*h1;
#pragma unroll
      for (int off = 32; off; off >>= 1) v += __shfl_down(v, off);
      if (lane == 0) ws[WS_LOG + b*48 + p0 + pp] = v;
    }
    __syncthreads();
  }
}

// ---------------- K3: greedy merge scan — 1024 threads, k-split 8 ways (r20 version) ----------------
__global__ __launch_bounds__(1024, 1) void k_tree(const int* __restrict__ lengths,
                                                  float* __restrict__ ws,
                                                  const float* __restrict__ w1g,
                                                  const float* __restrict__ b1g,
                                                  const float* __restrict__ w2g,
                                                  float* __restrict__ out) {
  __shared__ float rows[NL*ND];      // 48 KB
  __shared__ float part[16*NH];      // 8 KB
  __shared__ float logits[48];
  __shared__ int physIdx[48];
  __shared__ int lbA[48];
  __shared__ int rbA[48];
  __shared__ float invn[48];
  __shared__ float b1s[NH];
  __shared__ float w2s[NH];
  __shared__ float red[8];
  __shared__ int s_idx, s_rL;
  __shared__ float s_tp, s_max;

  int b = blockIdx.x;
  int t = threadIdx.x;               // 0..1023
  int lane = t & 63, wv = t >> 6;    // 16 waves
  int j = t & 127, s8 = t >> 7;      // output unit j, k-segment s8 in [0,8)
  int len = lengths[b];

  // w1 segment pinned in registers: 64 VGPR (k-range s8*64..+64 of output j)
  float w1f[64];
  {
    const float4* wsrc = (const float4*)(w1g + (size_t)j*512 + s8*64);
#pragma unroll
    for (int kk = 0; kk < 16; ++kk) {
      float4 v = wsrc[kk];
      w1f[4*kk+0] = v.x; w1f[4*kk+1] = v.y; w1f[4*kk+2] = v.z; w1f[4*kk+3] = v.w;
    }
  }
#pragma unroll
  for (int kk = 0; kk < 16; ++kk)
    asm volatile("" : "+v"(w1f[4*kk+0]), "+v"(w1f[4*kk+1]), "+v"(w1f[4*kk+2]), "+v"(w1f[4*kk+3]));

  if (t < NH) { b1s[t] = b1g[t]; w2s[t] = w2g[t]; }
  if (t < 48) { physIdx[t] = t; lbA[t] = t; rbA[t] = t; invn[t] = ws[WS_INVN + b*48 + t]; }
  if (t < 47) logits[t] = ws[WS_LOG + b*48 + t];
  {
    const float4* pg4 = (const float4*)(ws + WS_PHYS + (size_t)b*PB_STRIDE);
    float4* rows4 = (float4*)rows;
    for (int u = t; u < NL*64; u += 1024) rows4[u] = pg4[u];
  }
  __syncthreads();

  // GEMV partial for one pair-position: 16 loads + 64 FMAs
  auto gemv_pos = [&](int pos, int slot) {
    int r = (s8 < 4) ? physIdx[pos + 1] : physIdx[pos];
    const float4* rp4 = (const float4*)(rows + r*ND + (s8 & 3)*64);
    float ax = 0.f, ay = 0.f, az = 0.f, aw = 0.f;
#pragma unroll
    for (int kk = 0; kk < 16; ++kk) {
      float4 rv = rp4[kk];
      ax = fmaf(w1f[4*kk+0], rv.x, ax);
      ay = fmaf(w1f[4*kk+1], rv.y, ay);
      az = fmaf(w1f[4*kk+2], rv.z, az);
      aw = fmaf(w1f[4*kk+3], rv.w, aw);
    }
    part[(s8*2 + slot)*NH + j] = (ax + ay) + (az + aw);
  };

  int pidx = -1;
  for (int i = 0; i < NS; ++i) {
    int valid = len - 1 - i; if (valid < 0) valid = 0;
    // ---- R1: deferred invn update for previous merged slot ----
    if (i > 0 && t == 0)
      invn[s_rL] = 1.0f / (sqrtf(red[4]+red[5]+red[6]+red[7]) + EPSF);
    if (valid >= 2) {
      if (i > 0) {
        int pos0 = -1, pos1 = -1, np = 0;
        if (pidx > 0) { pos0 = pidx - 1; np = 1; }
        if (pidx <= valid - 1) { if (np) pos1 = pidx; else pos0 = pidx; ++np; }
        gemv_pos(pos0, 0);
        if (np > 1) gemv_pos(pos1, 1);
        ldsbar();                              // B1 (LDS: part, invn)
        if (wv < np) {
          int p = (wv == 0) ? pos0 : pos1;
          int rR = physIdx[p + 1], rLL = physIdx[p];
          float inR = invn[rR], inL = invn[rLL];
          // sum 4 segment-partials per 256-half, pairwise
          float pr0 = (part[(0*2+wv)*NH + lane]      + part[(1*2+wv)*NH + lane])
                    + (part[(2*2+wv)*NH + lane]      + part[(3*2+wv)*NH + lane]);
          float pl0 = (part[(4*2+wv)*NH + lane]      + part[(5*2+wv)*NH + lane])
                    + (part[(6*2+wv)*NH + lane]      + part[(7*2+wv)*NH + lane]);
          float pr1 = (part[(0*2+wv)*NH + lane + 64] + part[(1*2+wv)*NH + lane + 64])
                    + (part[(2*2+wv)*NH + lane + 64] + part[(3*2+wv)*NH + lane + 64]);
          float pl1 = (part[(4*2+wv)*NH + lane + 64] + part[(5*2+wv)*NH + lane + 64])
                    + (part[(6*2+wv)*NH + lane + 64] + part[(7*2+wv)*NH + lane + 64]);
          float h0 = fmaf(inR, pr0, fmaf(inL, pl0, b1s[lane]));
          float h1 = fmaf(inR, pr1, fmaf(inL, pl1, b1s[lane + 64]));
          h0 = fmaxf(h0, 0.f); h1 = fmaxf(h1, 0.f);
          float v = w2s[lane]*h0 + w2s[lane + 64]*h1;
#pragma unroll
          for (int off = 32; off; off >>= 1) v += __shfl_down(v, off);
          if (lane == 0) logits[p] = v;
        }
        ldsbar();                              // B2 (LDS: logits)
      }
      // ---- R3: argmax (first occurrence) over domain, wave 0 ----
      if (wv == 0) {
        float v = (lane < valid) ? logits[lane] : -INFINITY;
        int bi = lane;
#pragma unroll
        for (int off = 32; off; off >>= 1) {
          float ov = __shfl_down(v, off);
          int  oi = __shfl_down(bi, off);
          if (ov > v || (ov == v && oi < bi)) { v = ov; bi = oi; }
        }
        if (lane == 0) { s_idx = bi; s_max = v; }
      }
    } else {
      // valid==1: idx=0, tp=1. valid==0: all logits bitwise -1e10 -> uniform: idx=0, tp=1/47.
      if (t == 0) { s_idx = 0; s_tp = (valid == 1) ? 1.0f : (1.0f/47.0f); }
    }
    ldsbar();                                  // B3 (LDS: s_idx, s_max)
    int idx = s_idx;
    // ---- R4: merge gather (waves 0-3) || softmax sum (wave 4) || pre-reads (wave 5) ----
    int rL = 0, rR = 0; float slv = 0.f, srv = 0.f, inL = 0.f, inR = 0.f, sumv = 0.f;
    if (t < ND) {
      rL = physIdx[idx]; rR = physIdx[idx + 1];
      slv = rows[rL*ND + t]; srv = rows[rR*ND + t];
      inL = invn[rL]; inR = invn[rR];
      sumv = slv + srv;
      float q2 = sumv * sumv;
#pragma unroll
      for (int off = 32; off; off >>= 1) q2 += __shfl_down(q2, off);
      if (lane == 0) red[wv] = q2;
    }
    int sp0 = 0, sp1 = 0;
    if (t == 0) { s_rL = rL; sp0 = lbA[idx]; sp1 = rbA[idx + 1]; }
    if (wv == 4 && valid >= 2) {
      float ee = (lane < valid) ? expf(logits[lane] - s_max) : 0.f;
#pragma unroll
      for (int off = 32; off; off >>= 1) ee += __shfl_down(ee, off);
      if (lane == 0) s_tp = 1.0f / ee;
    }
    int tt = t - 320;
    int pv = 0, lv = 0, rv_ = 0; float gv = 0.f;
    if (wv == 5 && tt < 47) { pv = physIdx[tt+1]; lv = lbA[tt+1]; rv_ = rbA[tt+1]; gv = logits[tt+1]; }
    ldsbar();                                  // B4 (LDS: red, s_tp, pre-reads)
    // ---- R5: outputs, row update, bookkeeping shifts ----
    float undone = valid > 0 ? 1.0f : 0.0f;
    if (t < ND) {
      float invns = 1.0f / (sqrtf(red[0]+red[1]+red[2]+red[3]) + EPSF);
      float featv = sumv * invns;
      int ob = (i*NB + b)*ND + t;
      out[O_FEAT  + ob] = featv * undone;
      out[O_LEFT  + ob] = slv * inL * undone;
      out[O_RIGHT + ob] = srv * inR * undone;
      rows[rL*ND + t] = featv;
      float q3 = featv * featv;
#pragma unroll
      for (int off = 32; off; off >>= 1) q3 += __shfl_down(q3, off);
      if (lane == 0) red[4 + wv] = q3;
    }
    if (t == 0) {
      out[O_TIDX + i*NB + b] = (float)idx;
      out[O_TP   + i*NB + b] = s_tp;
      out[O_SPAN + (i*NB + b)*2 + 0] = (float)sp0;
      out[O_SPAN + (i*NB + b)*2 + 1] = (float)sp1;
    }
    if (wv == 5 && tt < 47) {
      if (tt > idx) { physIdx[tt] = pv; lbA[tt] = lv; logits[tt] = gv; }
      if (tt >= idx) rbA[tt] = rv_;
    }
    ldsbar();                                  // B5 (LDS: rows/logits/bookkeeping/red)
    pidx = idx;
  }
}

extern "C" void kernel_launch(void* const* d_in, const int* in_sizes, int n_in,
                              void* d_out, int out_size, void* d_ws, size_t ws_size,
                              hipStream_t stream) {
  const float* x      = (const float*)d_in[0];
  const int*   lengths= (const int*)  d_in[1];
  const float* amask  = (const float*)d_in[2];
  const float* w_sem  = (const float*)d_in[3];
  const float* w1     = (const float*)d_in[4];
  const float* b1     = (const float*)d_in[5];
  const float* w2     = (const float*)d_in[6];
  float* out = (float*)d_out;
  float* ws  = (float*)d_ws;

  k_transpose<<<dim3(256), dim3(256), 0, stream>>>(w_sem, ws);
  k_sem0<<<dim3(NB*NL/2), dim3(128), 0, stream>>>(x, lengths, amask, ws, out);
  k_prelogits<<<dim3(256), dim3(512), 0, stream>>>(ws, lengths, w1, b1, w2);
  k_tree<<<dim3(NB), dim3(1024), 0, stream>>>(lengths, ws, w1, b1, w2, out);
}